// Round 2
// baseline (388.895 us; speedup 1.0000x reference)
//
#include <hip/hip_runtime.h>
#include <hip/hip_bf16.h>
#include <cstdint>

typedef __attribute__((ext_vector_type(8))) short short8_t;
typedef __attribute__((ext_vector_type(4))) short s16x4;
typedef __attribute__((ext_vector_type(4))) float f32x4;

#define SEQ 2048
#define BATCH 2
#define DM 2048
#define NH 16
#define HD 128
#define SCALE 0.08838834764831845f  // 1/sqrt(128)

__device__ __forceinline__ short f2bf(float f) {
    union { __hip_bfloat16 h; short s; } u; u.h = __float2bfloat16(f); return u.s;
}
__device__ __forceinline__ float bf2f(short s) {
    union { short s; __hip_bfloat16 h; } u; u.s = s; return __bfloat162float(u.h);
}

// ---------------- RoPE table ----------------
__global__ void rope_table_kernel(float* __restrict__ cosT, float* __restrict__ sinT) {
    int t = blockIdx.x;
    int i = threadIdx.x;
    float inv = exp2f(-(2.0f * (float)i / 128.0f) * log2f(10000.0f));
    float a = (float)t * inv;
    cosT[t * 64 + i] = cosf(a);
    sinT[t * 64 + i] = sinf(a);
}

// ---------------- fused f32 -> bf16 cast of 4 weight matrices ----------------
__global__ void cast4_kernel(const float* __restrict__ qw, const float* __restrict__ kw,
                             const float* __restrict__ vw, const float* __restrict__ ow,
                             short* __restrict__ out) {
    // out layout: [qw | kw | vw | ow], each DM*DM bf16. Process float4 units.
    const int per = DM * DM / 4;
    int i = blockIdx.x * blockDim.x + threadIdx.x;
    int stride = gridDim.x * blockDim.x;
    for (; i < 4 * per; i += stride) {
        int region = i / per;
        int off = i - region * per;
        const float* src = region == 0 ? qw : (region == 1 ? kw : (region == 2 ? vw : ow));
        float4 v = ((const float4*)src)[off];
        s16x4 o;
        o[0] = f2bf(v.x); o[1] = f2bf(v.y); o[2] = f2bf(v.z); o[3] = f2bf(v.w);
        ((s16x4*)(out + (size_t)region * DM * DM))[off] = o;
    }
}

// ---------------- L2 norm + scale + cast ----------------
__global__ void __launch_bounds__(256) norm_cast_kernel(const float* __restrict__ x,
                                                        const float* __restrict__ w,
                                                        short* __restrict__ xn) {
    __shared__ float red[4];
    int row = blockIdx.x;
    const float* xr = x + (size_t)row * DM;
    short* outr = xn + (size_t)row * DM;
    int t = threadIdx.x;
    float vals[8];
    float ss = 0.f;
#pragma unroll
    for (int i = 0; i < 8; ++i) { float v = xr[t + 256 * i]; vals[i] = v; ss += v * v; }
#pragma unroll
    for (int off = 1; off < 64; off <<= 1) ss += __shfl_xor(ss, off);
    int lane = t & 63, wv = t >> 6;
    if (lane == 0) red[wv] = ss;
    __syncthreads();
    float tot = red[0] + red[1] + red[2] + red[3];
    float inv = 1.f / (sqrtf(tot) + 1e-5f);
#pragma unroll
    for (int i = 0; i < 8; ++i)
        outr[t + 256 * i] = f2bf(vals[i] * inv * w[t + 256 * i]);
}

// ================= 256x256 deep-pipelined BT GEMM =================
// C[m][n] = sum_k A[m][k]*B[n][k]; bf16 in, f32 acc.
// 512 threads (8 waves, 2Mx4N), BK=32 per ring slot, 4-slot LDS ring (128 KiB),
// counted vmcnt (8 in steady state), 2 phases x 16 MFMA per K-step, setprio,
// XOR 16B-slot swizzle via pre-swizzled global source (linear global_load_lds dest).
// MODE 0: QKV scatter epilogue. MODE 1: f32 out + bias epilogue.

__device__ __forceinline__ void stage_tile(const short* __restrict__ A,
                                           const short* __restrict__ B,
                                           short* lds, int slot, int kb, int K,
                                           int brow, int bcol, int w, int lane) {
    short* abase = lds + slot * 8192;
    short* bbase = lds + 32768 + slot * 8192;
    const int l4r = lane >> 2;                       // row within 16-row chunk
    const int slog = (lane & 3) ^ ((lane >> 3) & 3); // pre-swizzled logical 16B slot
#pragma unroll
    for (int j = 0; j < 2; ++j) {
        int row = w * 32 + j * 16 + l4r;
        const short* ga = A + (size_t)(brow + row) * K + kb + slog * 8;
        const short* gb = B + (size_t)(bcol + row) * K + kb + slog * 8;
        __builtin_amdgcn_global_load_lds((const __attribute__((address_space(1))) void*)ga,
                                         (__attribute__((address_space(3))) void*)(abase + (w * 32 + j * 16) * 32),
                                         16, 0, 0);
        __builtin_amdgcn_global_load_lds((const __attribute__((address_space(1))) void*)gb,
                                         (__attribute__((address_space(3))) void*)(bbase + (w * 32 + j * 16) * 32),
                                         16, 0, 0);
    }
}

template <int MODE>
__global__ void __launch_bounds__(512, 2) gemm256(const short* __restrict__ A,
                                                  const short* __restrict__ B,
                                                  int Mt, int Nt, int N, int K,
                                                  short* __restrict__ oq, short* __restrict__ ok,
                                                  short* __restrict__ ov,
                                                  const float* __restrict__ bq,
                                                  const float* __restrict__ bk,
                                                  const float* __restrict__ bv,
                                                  float* __restrict__ outF,
                                                  const float* __restrict__ bias) {
    extern __shared__ short lds[];   // 4*(8192 A + 8192 B) shorts = 128 KiB
    const int tid = threadIdx.x;
    const int lane = tid & 63;
    const int w = tid >> 6;
    const int wr = w >> 2;           // 0..1
    const int wc = w & 3;            // 0..3

    // bijective XCD swizzle (nwg % 8 == 0 for both call sites)
    const int nwg = Mt * Nt;
    const int cpx = nwg >> 3;
    const int bid = blockIdx.x;
    const int swz = (bid & 7) * cpx + (bid >> 3);
    const int brow = (swz % Mt) * 256;
    const int bcol = (swz / Mt) * 256;

    const int fr = lane & 15;
    const int fk = lane >> 4;                 // logical 16B slot 0..3
    const int rsw = (fr >> 1) & 3;            // row-derived swizzle term
    const int fcol = (fk ^ rsw) * 8;          // physical slot offset in shorts

    f32x4 acc[8][4];
#pragma unroll
    for (int i = 0; i < 8; ++i)
#pragma unroll
        for (int j = 0; j < 4; ++j) acc[i][j] = (f32x4){0.f, 0.f, 0.f, 0.f};

    const int nt = K / 32;
    stage_tile(A, B, lds, 0, 0, K, brow, bcol, w, lane);
    stage_tile(A, B, lds, 1, 32, K, brow, bcol, w, lane);
    stage_tile(A, B, lds, 2, 64, K, brow, bcol, w, lane);

    for (int t = 0; t < nt; ++t) {
        // slot-ready guard: own loads for tile t complete, up to 8 (2 tiles) stay in flight
        if (t + 3 <= nt - 1)      asm volatile("s_waitcnt vmcnt(8)" ::: "memory");
        else if (t + 2 == nt - 1) asm volatile("s_waitcnt vmcnt(4)" ::: "memory");
        else                      asm volatile("s_waitcnt vmcnt(0)" ::: "memory");
        asm volatile("s_barrier" ::: "memory");

        const short* sa = lds + (t & 3) * 8192;
        const short* sb = lds + 32768 + (t & 3) * 8192;

        short8_t bfrag[4];
#pragma unroll
        for (int j = 0; j < 4; ++j)
            bfrag[j] = *(const short8_t*)&sb[(wc * 64 + j * 16 + fr) * 32 + fcol];
        short8_t afrag[4];
#pragma unroll
        for (int i = 0; i < 4; ++i)
            afrag[i] = *(const short8_t*)&sa[(wr * 128 + i * 16 + fr) * 32 + fcol];

        // prefetch tile t+3 into the slot freed at this iteration's leading barrier
        if (t + 3 < nt)
            stage_tile(A, B, lds, (t + 3) & 3, (t + 3) * 32, K, brow, bcol, w, lane);

        __builtin_amdgcn_s_setprio(1);
#pragma unroll
        for (int i = 0; i < 4; ++i)
#pragma unroll
            for (int j = 0; j < 4; ++j)
                acc[i][j] = __builtin_amdgcn_mfma_f32_16x16x32_bf16(afrag[i], bfrag[j], acc[i][j], 0, 0, 0);
        __builtin_amdgcn_s_setprio(0);
        asm volatile("s_barrier" ::: "memory");

        short8_t afrag2[4];
#pragma unroll
        for (int i = 0; i < 4; ++i)
            afrag2[i] = *(const short8_t*)&sa[(wr * 128 + (i + 4) * 16 + fr) * 32 + fcol];
        __builtin_amdgcn_s_setprio(1);
#pragma unroll
        for (int i = 0; i < 4; ++i)
#pragma unroll
            for (int j = 0; j < 4; ++j)
                acc[i + 4][j] = __builtin_amdgcn_mfma_f32_16x16x32_bf16(afrag2[i], bfrag[j], acc[i + 4][j], 0, 0, 0);
        __builtin_amdgcn_s_setprio(0);
    }

    // epilogue: C frag layout col = lane&15 (n), row = (lane>>4)*4 + jj (m)
    const int fq = (lane >> 4) * 4;
#pragma unroll
    for (int i = 0; i < 8; ++i) {
        int mrow = brow + wr * 128 + i * 16 + fq;
#pragma unroll
        for (int j = 0; j < 4; ++j) {
            int ncol = bcol + wc * 64 + j * 16 + fr;
            if (MODE == 0) {
                int which = ncol >> 11;
                int hl = ncol & 2047;
                int h = hl >> 7, d = hl & 127;
                const float* bp = which == 0 ? bq : (which == 1 ? bk : bv);
                short* dst = which == 0 ? oq : (which == 1 ? ok : ov);
                float bval = bp[hl];
#pragma unroll
                for (int jj = 0; jj < 4; ++jj) {
                    int m = mrow + jj;
                    int s = m >> 1, b = m & 1;
                    float v = acc[i][j][jj] + bval;
                    size_t idx;
                    if (which == 2)
                        idx = (((size_t)(b * NH + h)) * HD + d) * SEQ + s;   // V transposed (b,h,d,s)
                    else
                        idx = (((size_t)(b * NH + h)) * SEQ + s) * HD + d;   // (b,h,s,d)
                    dst[idx] = f2bf(v);
                }
            } else {
                float bval = bias[ncol];
#pragma unroll
                for (int jj = 0; jj < 4; ++jj) {
                    int m = mrow + jj;
                    outF[(size_t)m * N + ncol] = acc[i][j][jj] + bval;
                }
            }
        }
    }
}

// ---------------- RoPE in-place on q,k (b,h,s,d) bf16 ----------------
__global__ void __launch_bounds__(256) rope_kernel(short* __restrict__ q, short* __restrict__ k,
                                                   const float* __restrict__ cosT,
                                                   const float* __restrict__ sinT) {
    int w = threadIdx.x >> 6, lane = threadIdx.x & 63;
    int idx = blockIdx.x * 4 + w;
    int s = idx & (SEQ - 1);
    size_t base = (size_t)idx * HD;
    float c = cosT[s * 64 + lane], sn = sinT[s * 64 + lane];
    float q1 = bf2f(q[base + lane]), q2 = bf2f(q[base + lane + 64]);
    q[base + lane] = f2bf(q1 * c - q2 * sn);
    q[base + lane + 64] = f2bf(q2 * c + q1 * sn);
    float k1 = bf2f(k[base + lane]), k2 = bf2f(k[base + lane + 64]);
    k[base + lane] = f2bf(k1 * c - k2 * sn);
    k[base + lane + 64] = f2bf(k2 * c + k1 * sn);
}

// ---------------- Flash attention (causal), 4 waves x 16 q-rows, KV tile 64 ----------
__global__ void __launch_bounds__(256) attn_kernel(const short* __restrict__ Q,
                                                   const short* __restrict__ K,
                                                   const short* __restrict__ V,
                                                   short* __restrict__ AO) {
    __shared__ short Kl[64 * 136];
    __shared__ short Vt[128 * 88];
    __shared__ short Pl[4][16 * 88];

    const int bh = blockIdx.x;
    const int qt = blockIdx.y;
    const int b = bh >> 4;
    const int h = bh & 15;
    const size_t base = (size_t)bh * (SEQ * HD);
    const int tid = threadIdx.x;
    const int lane = tid & 63;
    const int w = tid >> 6;
    const int fr = lane & 15;
    const int fk = (lane >> 4) * 8;
    const int fq = (lane >> 4) * 4;
    const int qbase = qt * 64 + w * 16;
    const int qg = qbase + fr;

    short8_t qf[4];
#pragma unroll
    for (int kc = 0; kc < 4; ++kc)
        qf[kc] = *(const short8_t*)&Q[base + (size_t)(qbase + fr) * HD + kc * 32 + fk];

    f32x4 acc[8];
#pragma unroll
    for (int dt = 0; dt < 8; ++dt) acc[dt] = (f32x4){0.f, 0.f, 0.f, 0.f};
    float m_r = -1e30f, l_r = 0.f;

    for (int kt = 0; kt <= qt; ++kt) {
#pragma unroll
        for (int p = 0; p < 4; ++p) {
            int idx = p * 256 + tid;
            int r = idx >> 4;
            int c8 = (idx & 15) * 8;
            *(short8_t*)&Kl[r * 136 + c8] =
                *(const short8_t*)&K[base + (size_t)(kt * 64 + r) * HD + c8];
        }
#pragma unroll
        for (int p = 0; p < 4; ++p) {
            int idx = p * 256 + tid;
            int d = idx >> 3;
            int c8 = (idx & 7) * 8;
            *(short8_t*)&Vt[d * 88 + c8] =
                *(const short8_t*)&V[base + (size_t)d * SEQ + kt * 64 + c8];
        }
        __syncthreads();

        f32x4 st[4];
#pragma unroll
        for (int nt = 0; nt < 4; ++nt) {
            f32x4 a = (f32x4){0.f, 0.f, 0.f, 0.f};
#pragma unroll
            for (int kc = 0; kc < 4; ++kc) {
                short8_t kf = *(const short8_t*)&Kl[(nt * 16 + fr) * 136 + kc * 32 + fk];
                a = __builtin_amdgcn_mfma_f32_16x16x32_bf16(kf, qf[kc], a, 0, 0, 0);
            }
            st[nt] = a;
        }

        float rmax = -1e30f;
#pragma unroll
        for (int nt = 0; nt < 4; ++nt) {
#pragma unroll
            for (int jj = 0; jj < 4; ++jj) {
                int kg = kt * 64 + nt * 16 + fq + jj;
                float sv = st[nt][jj];
                sv = (kg > qg) ? -1e30f : sv;
                st[nt][jj] = sv;
                rmax = fmaxf(rmax, sv);
            }
        }
        rmax = fmaxf(rmax, __shfl_xor(rmax, 16));
        rmax = fmaxf(rmax, __shfl_xor(rmax, 32));
        float m_new = fmaxf(m_r, rmax);
        float corr = __expf((m_r - m_new) * SCALE);
        float rsum = 0.f;
#pragma unroll
        for (int nt = 0; nt < 4; ++nt) {
            s16x4 pk;
#pragma unroll
            for (int jj = 0; jj < 4; ++jj) {
                float p = __expf((st[nt][jj] - m_new) * SCALE);
                rsum += p;
                pk[jj] = f2bf(p);
            }
            *(s16x4*)&Pl[w][fr * 88 + nt * 16 + fq] = pk;
        }
        rsum += __shfl_xor(rsum, 16);
        rsum += __shfl_xor(rsum, 32);
        l_r = l_r * corr + rsum;
        m_r = m_new;

        float c4[4];
#pragma unroll
        for (int jj = 0; jj < 4; ++jj) c4[jj] = __shfl(corr, fq + jj);
#pragma unroll
        for (int dt = 0; dt < 8; ++dt) {
#pragma unroll
            for (int jj = 0; jj < 4; ++jj) acc[dt][jj] *= c4[jj];
        }

#pragma unroll
        for (int kc = 0; kc < 2; ++kc) {
            short8_t pf = *(const short8_t*)&Pl[w][fr * 88 + kc * 32 + fk];
#pragma unroll
            for (int dt = 0; dt < 8; ++dt) {
                short8_t vf = *(const short8_t*)&Vt[(dt * 16 + fr) * 88 + kc * 32 + fk];
                acc[dt] = __builtin_amdgcn_mfma_f32_16x16x32_bf16(pf, vf, acc[dt], 0, 0, 0);
            }
        }
        __syncthreads();
    }

    float linv[4];
#pragma unroll
    for (int jj = 0; jj < 4; ++jj) linv[jj] = 1.f / __shfl(l_r, fq + jj);
#pragma unroll
    for (int dt = 0; dt < 8; ++dt) {
#pragma unroll
        for (int jj = 0; jj < 4; ++jj) {
            int qrow = qbase + fq + jj;
            int d = dt * 16 + fr;
            AO[((size_t)(qrow * BATCH + b)) * DM + h * HD + d] = f2bf(acc[dt][jj] * linv[jj]);
        }
    }
}

extern "C" void kernel_launch(void* const* d_in, const int* in_sizes, int n_in,
                              void* d_out, int out_size, void* d_ws, size_t ws_size,
                              hipStream_t stream) {
    (void)in_sizes; (void)n_in; (void)out_size; (void)ws_size;
    const float* x  = (const float*)d_in[0];
    const float* nw = (const float*)d_in[3];
    const float* qw = (const float*)d_in[4];
    const float* qbias = (const float*)d_in[5];
    const float* kw = (const float*)d_in[6];
    const float* kbias = (const float*)d_in[7];
    const float* vw = (const float*)d_in[8];
    const float* vbias = (const float*)d_in[9];
    const float* ow = (const float*)d_in[10];
    const float* obias = (const float*)d_in[11];
    float* out = (float*)d_out;

    char* ws = (char*)d_ws;
    size_t off = 0;
    float* cosT = (float*)(ws + off); off += (size_t)SEQ * 64 * 4;
    float* sinT = (float*)(ws + off); off += (size_t)SEQ * 64 * 4;
    short* wqkv = (short*)(ws + off); off += (size_t)3 * DM * DM * 2;
    short* wo   = (short*)(ws + off); off += (size_t)DM * DM * 2;
    short* xn   = (short*)(ws + off); off += (size_t)SEQ * BATCH * DM * 2;  // reused as AO
    short* qd   = (short*)(ws + off); off += (size_t)SEQ * BATCH * DM * 2;
    short* kd   = (short*)(ws + off); off += (size_t)SEQ * BATCH * DM * 2;
    short* vd   = (short*)(ws + off); off += (size_t)SEQ * BATCH * DM * 2;
    short* ao   = xn;

    // allow 128 KiB dynamic LDS (idempotent; host-side, graph-capture safe)
    hipFuncSetAttribute((const void*)gemm256<0>, hipFuncAttributeMaxDynamicSharedMemorySize, 131072);
    hipFuncSetAttribute((const void*)gemm256<1>, hipFuncAttributeMaxDynamicSharedMemorySize, 131072);

    rope_table_kernel<<<SEQ, 64, 0, stream>>>(cosT, sinT);
    cast4_kernel<<<2048, 256, 0, stream>>>(qw, kw, vw, ow, wqkv);
    norm_cast_kernel<<<SEQ * BATCH, 256, 0, stream>>>(x, nw, xn);
    gemm256<0><<<dim3(16 * 24), 512, 131072, stream>>>(
        xn, wqkv, 16, 24, 3 * DM, DM, qd, kd, vd, qbias, kbias, vbias, nullptr, nullptr);
    rope_kernel<<<BATCH * NH * SEQ / 4, 256, 0, stream>>>(qd, kd, cosT, sinT);
    attn_kernel<<<dim3(BATCH * NH, SEQ / 64), 256, 0, stream>>>(qd, kd, vd, ao);
    gemm256<1><<<dim3(16 * 8), 512, 131072, stream>>>(
        ao, wo + (size_t)3 * DM * DM - (size_t)3 * DM * DM, 16, 8, DM, DM,
        nullptr, nullptr, nullptr, nullptr, nullptr, nullptr, out, obias);
}